// Round 6
// baseline (5405.468 us; speedup 1.0000x reference)
//
#include <hip/hip_runtime.h>
#include <hip/hip_bf16.h>

// Problem constants
#define BB   4096
#define TT   128
#define OBS  64
#define ACT  16
#define DD   64
#define HH   256
#define G4   1024   // 4*H
#define BD   262144 // B*D

// LDS A-tile row stride in shorts: 320 data + 4 pad.
#define ASTR 324
#define ATILE (32 * ASTR)

typedef short bshort8 __attribute__((ext_vector_type(8)));
typedef float f32x4  __attribute__((ext_vector_type(4)));

__device__ __forceinline__ unsigned short f2bf(float f) {
    union { float f; unsigned int u; } v; v.f = f;
    unsigned int u = v.u;
    u += 0x7FFFu + ((u >> 16) & 1u);   // RNE
    return (unsigned short)(u >> 16);
}
__device__ __forceinline__ float bf2f(unsigned short s) {
    union { unsigned int u; float f; } v; v.u = ((unsigned int)s) << 16;
    return v.f;
}

// ---------------- pack weights: Wt[ko][col][j] = B[8*ko+j][col], bf16 -------
// B = [Wx (64 rows) ; Wh (256 rows)] -> K = 320 = 40 k-octs, 1024 cols
__global__ void pack_wt(const float* __restrict__ Wx, const float* __restrict__ Wh,
                        unsigned short* __restrict__ wt) {
    int idx = blockIdx.x * 256 + threadIdx.x;      // < 40*1024*8 = 327680
    int j   = idx & 7;
    int col = (idx >> 3) & 1023;
    int ko  = idx >> 13;
    int k   = ko * 8 + j;
    float v = (k < 64) ? Wx[k * 1024 + col] : Wh[(k - 64) * 1024 + col];
    wt[idx] = f2bf(v);
}

// ---------------- embed: one block per batch row b, all 128 timesteps -------
__global__ void __launch_bounds__(256)
embed_tiled(const float* __restrict__ obs, const float* __restrict__ act,
            const float* __restrict__ We,  const float* __restrict__ be,
            unsigned short* __restrict__ x) {
    int b   = blockIdx.x;
    int tid = threadIdx.x;
    __shared__ __align__(16) float A[128 * 84];
    __shared__ __align__(16) float W[80 * 64];

    for (int i = tid; i < 1280; i += 256)
        *reinterpret_cast<f32x4*>(&W[i * 4]) = *reinterpret_cast<const f32x4*>(&We[i * 4]);
    const float* ob = obs + (size_t)b * (TT * OBS);
#pragma unroll
    for (int it = 0; it < 8; ++it) {
        int i4 = tid + it * 256;
        f32x4 v = *reinterpret_cast<const f32x4*>(ob + i4 * 4);
        int e = i4 * 4, t = e >> 6, f = e & 63;
        *reinterpret_cast<f32x4*>(&A[t * 84 + f]) = v;
    }
    const float* ar = act + (size_t)b * (TT * ACT);
#pragma unroll
    for (int it = 0; it < 2; ++it) {
        int i4 = tid + it * 256;
        f32x4 v = *reinterpret_cast<const f32x4*>(ar + i4 * 4);
        int e = i4 * 4, t = e >> 4, f = e & 15;
        *reinterpret_cast<f32x4*>(&A[t * 84 + 64 + f]) = v;
    }
    __syncthreads();

    int rg = tid & 15, cg = tid >> 4;
    int c0 = cg * 4;
    float acc[8][4];
    float be0 = be[c0], be1 = be[c0 + 1], be2 = be[c0 + 2], be3 = be[c0 + 3];
#pragma unroll
    for (int i = 0; i < 8; ++i) {
        acc[i][0] = be0; acc[i][1] = be1; acc[i][2] = be2; acc[i][3] = be3;
    }

    for (int kq = 0; kq < 20; ++kq) {
        f32x4 A4[8];
#pragma unroll
        for (int i = 0; i < 8; ++i)
            A4[i] = *reinterpret_cast<const f32x4*>(&A[(rg + 16 * i) * 84 + kq * 4]);
        f32x4 W0 = *reinterpret_cast<const f32x4*>(&W[(kq * 4 + 0) * 64 + c0]);
        f32x4 W1 = *reinterpret_cast<const f32x4*>(&W[(kq * 4 + 1) * 64 + c0]);
        f32x4 W2 = *reinterpret_cast<const f32x4*>(&W[(kq * 4 + 2) * 64 + c0]);
        f32x4 W3 = *reinterpret_cast<const f32x4*>(&W[(kq * 4 + 3) * 64 + c0]);
#pragma unroll
        for (int i = 0; i < 8; ++i) {
#pragma unroll
            for (int j = 0; j < 4; ++j) {
                acc[i][j] += A4[i][0] * W0[j] + A4[i][1] * W1[j]
                           + A4[i][2] * W2[j] + A4[i][3] * W3[j];
            }
        }
    }

#pragma unroll
    for (int i = 0; i < 8; ++i) {
        int t = rg + 16 * i;
        unsigned int lo = (unsigned)f2bf(acc[i][0]) | ((unsigned)f2bf(acc[i][1]) << 16);
        unsigned int hi = (unsigned)f2bf(acc[i][2]) | ((unsigned)f2bf(acc[i][3]) << 16);
        *reinterpret_cast<uint2*>(x + ((size_t)t * BB + b) * DD + c0) = make_uint2(lo, hi);
    }
}

// ---------------- BN partial stats from bf16 x: p[t][slice][64] -------------
__global__ void stats_x(const unsigned short* __restrict__ x,
                        float* __restrict__ p1, float* __restrict__ p2) {
    int t = blockIdx.x, s = blockIdx.y;
    int tid = threadIdx.x;
    int dg = tid & 15, bl = tid >> 4;
    int d0 = dg * 4;
    float s1[4] = {0, 0, 0, 0}, s2[4] = {0, 0, 0, 0};
    const unsigned short* xt = x + (size_t)t * BB * DD;
    for (int it = 0; it < 32; ++it) {
        int b = s * 512 + it * 16 + bl;
        uint2 v = *reinterpret_cast<const uint2*>(xt + (size_t)b * DD + d0);
        const unsigned short* u = reinterpret_cast<const unsigned short*>(&v);
#pragma unroll
        for (int q = 0; q < 4; ++q) {
            float xv = bf2f(u[q]);
            s1[q] += xv; s2[q] += xv * xv;
        }
    }
    __shared__ float r1[16][64];
    __shared__ float r2[16][64];
#pragma unroll
    for (int q = 0; q < 4; ++q) { r1[bl][d0 + q] = s1[q]; r2[bl][d0 + q] = s2[q]; }
    __syncthreads();
    if (tid < 64) {
        float a = 0.f, b2 = 0.f;
        for (int g = 0; g < 16; ++g) { a += r1[g][tid]; b2 += r2[g][tid]; }
        size_t o = ((size_t)t * 8 + s) * 64 + tid;
        p1[o] = a; p2[o] = b2;
    }
}

// ---------------- BN stats finalize: a = rstd*scale, bb = bias - m*a ---------
__global__ void bn_stats(const float* __restrict__ p1, const float* __restrict__ p2,
                         const float* __restrict__ scale, const float* __restrict__ bias,
                         float* __restrict__ sa, float* __restrict__ sb) {
    int t = blockIdx.x, d = threadIdx.x;  // 64 threads
    float s1 = 0.f, s2 = 0.f;
    for (int c = 0; c < 8; ++c) {
        size_t o = ((size_t)t * 8 + c) * 64 + d;
        s1 += p1[o]; s2 += p2[o];
    }
    float m   = s1 * (1.0f / 4096.0f);
    float var = s2 * (1.0f / 4096.0f) - m * m;
    float a   = rsqrtf(var + 1e-5f) * scale[d];
    sa[t * 64 + d] = a;
    sb[t * 64 + d] = bias[d] - m * a;
}

// ---------------- fused LSTM: block owns 32 batch rows, NO cross-block dep ---
// grid 128 x 1024 threads (16 waves = 4 waves/SIMD for latency overlap).
// Wave w: row-half wr=w&1 (16 rows), col-slice wc=w>>1 (32 hidden cols in each
// of the 4 gate blocks). h lives in LDS, c in registers.
// One barrier per step via LDS A double-buffer.
__global__ void __launch_bounds__(1024, 4)
lstm_fused(const unsigned short* __restrict__ x, const unsigned short* __restrict__ wt,
           const float* __restrict__ sa, const float* __restrict__ sb,
           unsigned short* __restrict__ hf, const float* __restrict__ b_lstm) {
    extern __shared__ __align__(16) unsigned short Adyn[];  // 2 x [32][ASTR]

    int bid = blockIdx.x;
    int R0  = bid * 32;                 // first batch row owned by this block
    int tid = threadIdx.x;
    int lane = tid & 63, w = tid >> 6;  // wave 0..15
    int l15 = lane & 15, lhi = lane >> 4;
    int wr = w & 1;                     // row half (16 rows)
    int wc = w >> 1;                    // col slice 0..7
    int u0 = wc * 32 + l15;             // hidden col base (s adds 16)

    // gate biases for this thread's two columns
    float bl[4][2];
#pragma unroll
    for (int g = 0; g < 4; ++g) {
        bl[g][0] = b_lstm[g * 256 + u0];
        bl[g][1] = b_lstm[g * 256 + u0 + 16];
    }

    // ---- init buffer 0: zero h region (k=64..319), stage x_0 with BN fold ----
    if (tid < 512) {
        uint4 z = make_uint4(0, 0, 0, 0);
        int row = tid >> 4, oct = tid & 15;   // 32 rows x 16 of 32 octs...
        // cover 32 rows x 32 octs with 512 threads: 2 octs each
        *reinterpret_cast<uint4*>(&Adyn[row * ASTR + 64 + oct * 16]) = z;
        *reinterpret_cast<uint4*>(&Adyn[row * ASTR + 64 + oct * 16 + 8]) = z;
    }
    int xrow = tid >> 3, xoct = tid & 7, d0x = (tid & 7) * 8;
    if (tid < 256) {
        f32x4 a0 = *reinterpret_cast<const f32x4*>(sa + d0x);
        f32x4 a1 = *reinterpret_cast<const f32x4*>(sa + d0x + 4);
        f32x4 b0 = *reinterpret_cast<const f32x4*>(sb + d0x);
        f32x4 b1 = *reinterpret_cast<const f32x4*>(sb + d0x + 4);
        uint4 v = *reinterpret_cast<const uint4*>(x + ((size_t)(R0 + xrow)) * DD + d0x);
        unsigned short* uu = reinterpret_cast<unsigned short*>(&v);
#pragma unroll
        for (int q = 0; q < 4; ++q) {
            float y = a0[q] * bf2f(uu[q]) + b0[q];
            uu[q] = f2bf(y >= 0.f ? y : 0.2f * y);
            float y2 = a1[q] * bf2f(uu[4 + q]) + b1[q];
            uu[4 + q] = f2bf(y2 >= 0.f ? y2 : 0.2f * y2);
        }
        *reinterpret_cast<uint4*>(&Adyn[xrow * ASTR + xoct * 8]) = v;
    }
    __syncthreads();

    // c state in registers: creg[s][r]
    float creg[2][4];
#pragma unroll
    for (int s = 0; s < 2; ++s)
#pragma unroll
        for (int r = 0; r < 4; ++r) creg[s][r] = 0.f;

    const unsigned short* wb = wt + ((size_t)lhi * 1024 + u0) * 8;
    int aoff = (wr * 16 + l15) * ASTR + lhi * 8;

    for (int t = 0; t < TT; ++t) {
        unsigned short* Acur = Adyn + (t & 1) * ATILE;
        unsigned short* Anxt = Adyn + ((t + 1) & 1) * ATILE;

        // ---- prefetch x_{t+1} + BN coeffs (lands during k-loop) ----
        uint4 pf;
        f32x4 pa0, pa1, pb0, pb1;
        bool do_pf = (t + 1 < TT) && (tid < 256);
        if (do_pf) {
            pf  = *reinterpret_cast<const uint4*>(x + ((size_t)(t + 1) * BB + R0 + xrow) * DD + d0x);
            pa0 = *reinterpret_cast<const f32x4*>(sa + (t + 1) * 64 + d0x);
            pa1 = *reinterpret_cast<const f32x4*>(sa + (t + 1) * 64 + d0x + 4);
            pb0 = *reinterpret_cast<const f32x4*>(sb + (t + 1) * 64 + d0x);
            pb1 = *reinterpret_cast<const f32x4*>(sb + (t + 1) * 64 + d0x + 4);
        }

        // ---- k-loop: z = A @ W ----
        f32x4 acc[4][2];
#pragma unroll
        for (int g = 0; g < 4; ++g)
#pragma unroll
            for (int s = 0; s < 2; ++s) acc[g][s] = (f32x4)0.f;

#pragma unroll
        for (int i = 0; i < 10; ++i) {
            bshort8 a0 = *reinterpret_cast<const bshort8*>(&Acur[aoff + i * 32]);
            const unsigned short* wk = wb + (size_t)i * 32768;
            bshort8 bfr[4][2];
#pragma unroll
            for (int g = 0; g < 4; ++g)
#pragma unroll
                for (int s = 0; s < 2; ++s)
                    bfr[g][s] = *reinterpret_cast<const bshort8*>(wk + g * 2048 + s * 128);
#pragma unroll
            for (int g = 0; g < 4; ++g)
#pragma unroll
                for (int s = 0; s < 2; ++s)
                    acc[g][s] = __builtin_amdgcn_mfma_f32_16x16x32_bf16(a0, bfr[g][s], acc[g][s], 0, 0, 0);
        }

        // ---- gates + state update; h_t -> Anxt (global on last step) ----
        bool last = (t == TT - 1);
#pragma unroll
        for (int s = 0; s < 2; ++s) {
            int us = u0 + s * 16;
#pragma unroll
            for (int r = 0; r < 4; ++r) {
                int row = wr * 16 + lhi * 4 + r;
                float zi = acc[0][s][r] + bl[0][s];
                float zf = acc[1][s][r] + bl[1][s];
                float zg = acc[2][s][r] + bl[2][s];
                float zo = acc[3][s][r] + bl[3][s];
                float si = 1.f / (1.f + __expf(-zi));
                float sf = 1.f / (1.f + __expf(-zf));
                float so = 1.f / (1.f + __expf(-zo));
                float tg = 2.f / (1.f + __expf(-2.f * zg)) - 1.f;
                float cn = sf * creg[s][r] + si * tg;
                float tc = 2.f / (1.f + __expf(-2.f * cn)) - 1.f;
                creg[s][r] = cn;
                unsigned short hb = f2bf(so * tc);
                if (last)
                    hf[(size_t)(R0 + row) * HH + us] = hb;
                else
                    Anxt[row * ASTR + 64 + us] = hb;
            }
        }
        // ---- stage prefetched x_{t+1} into Anxt ----
        if (do_pf) {
            unsigned short* uu = reinterpret_cast<unsigned short*>(&pf);
#pragma unroll
            for (int q = 0; q < 4; ++q) {
                float y = pa0[q] * bf2f(uu[q]) + pb0[q];
                uu[q] = f2bf(y >= 0.f ? y : 0.2f * y);
                float y2 = pa1[q] * bf2f(uu[4 + q]) + pb1[q];
                uu[4 + q] = f2bf(y2 >= 0.f ? y2 : 0.2f * y2);
            }
            *reinterpret_cast<uint4*>(&Anxt[xrow * ASTR + xoct * 8]) = pf;
        }
        __syncthreads();   // Anxt ready; Acur free for reuse
    }
}

// ---------------- heads: mu = h@Wmu + bmu ; log_std clipped ------------------
__global__ void heads(const unsigned short* __restrict__ h,
                      const float* __restrict__ Wmu, const float* __restrict__ bmu,
                      const float* __restrict__ Wls, const float* __restrict__ bls,
                      float* __restrict__ out) {
    int tid = threadIdx.x;
    int b = blockIdx.x * 4 + (tid >> 6);
    int d = tid & 63;
    const unsigned short* hr = h + (size_t)b * HH;
    float mu = 0.f, ls = 0.f;
    for (int k = 0; k < HH; ++k) {
        float hv = bf2f(hr[k]);
        mu += hv * Wmu[k * 64 + d];
        ls += hv * Wls[k * 64 + d];
    }
    mu += bmu[d];
    ls += bls[d];
    ls = fminf(fmaxf(ls, -10.f), 2.f);
    out[(size_t)b * 64 + d] = mu;
    out[BD + (size_t)b * 64 + d] = ls;
}

extern "C" void kernel_launch(void* const* d_in, const int* in_sizes, int n_in,
                              void* d_out, int out_size, void* d_ws, size_t ws_size,
                              hipStream_t stream) {
    const float* obs = (const float*)d_in[0];
    const float* act = (const float*)d_in[1];
    const float* We  = (const float*)d_in[2];
    const float* be  = (const float*)d_in[3];
    const float* bns = (const float*)d_in[4];
    const float* bnb = (const float*)d_in[5];
    const float* Wx  = (const float*)d_in[6];
    const float* Wh  = (const float*)d_in[7];
    const float* bl  = (const float*)d_in[8];
    const float* Wmu = (const float*)d_in[9];
    const float* bmu = (const float*)d_in[10];
    const float* Wls = (const float*)d_in[11];
    const float* bls = (const float*)d_in[12];

    char* ws = (char*)d_ws;
    unsigned short* xbf = (unsigned short*)(ws + 0);            // 64MB (raw pre-BN bf16)
    unsigned short* wt  = (unsigned short*)(ws + 67108864);     // 640KB
    unsigned short* hfin= (unsigned short*)(ws + 67764224);     // 2MB (final h)
    float* p1           = (float*)(ws + 76152832);              // 256KB
    float* p2           = (float*)(ws + 78249984);              // 256KB
    float* sa           = (float*)(ws + 80347136);              // 32KB
    float* sb           = (float*)(ws + 80379904);              // 32KB

    pack_wt<<<1280, 256, 0, stream>>>(Wx, Wh, wt);
    embed_tiled<<<4096, 256, 0, stream>>>(obs, act, We, be, xbf);
    stats_x<<<dim3(128, 8), 256, 0, stream>>>(xbf, p1, p2);
    bn_stats<<<128, 64, 0, stream>>>(p1, p2, bns, bnb, sa, sb);

    // dynamic LDS: 2 * 32 * ASTR * 2B = 41472 B; 1 block/CU by VGPR (16 waves)
    lstm_fused<<<128, 1024, 41472, stream>>>(xbf, wt, sa, sb, hfin, bl);

    heads<<<1024, 256, 0, stream>>>(hfin, Wmu, bmu, Wls, bls, (float*)d_out);
}

// Round 7
// 2783.292 us; speedup vs baseline: 1.9421x; 1.9421x over previous
//
#include <hip/hip_runtime.h>
#include <hip/hip_bf16.h>

// Problem constants
#define BB   4096
#define TT   128
#define OBS  64
#define ACT  16
#define DD   64
#define HH   256
#define G4   1024   // 4*H
#define BD   262144 // B*D

// LDS A-tile row stride in shorts: 320 data + 4 pad.
#define ASTR 324
#define ATILE (32 * ASTR)
// weight ring: 2 slots x 64KB (32768 shorts) right after A
#define WSLOT 32768

typedef short bshort8 __attribute__((ext_vector_type(8)));
typedef float f32x4  __attribute__((ext_vector_type(4)));

typedef const __attribute__((address_space(1))) void* gas_t;
typedef __attribute__((address_space(3))) void* las_t;

__device__ __forceinline__ unsigned short f2bf(float f) {
    union { float f; unsigned int u; } v; v.f = f;
    unsigned int u = v.u;
    u += 0x7FFFu + ((u >> 16) & 1u);   // RNE
    return (unsigned short)(u >> 16);
}
__device__ __forceinline__ float bf2f(unsigned short s) {
    union { unsigned int u; float f; } v; v.u = ((unsigned int)s) << 16;
    return v.f;
}

// ---------------- pack weights: Wt[ko][col][j] = B[8*ko+j][col], bf16 -------
// B = [Wx (64 rows) ; Wh (256 rows)] -> K = 320 = 40 k-octs, 1024 cols
__global__ void pack_wt(const float* __restrict__ Wx, const float* __restrict__ Wh,
                        unsigned short* __restrict__ wt) {
    int idx = blockIdx.x * 256 + threadIdx.x;      // < 40*1024*8 = 327680
    int j   = idx & 7;
    int col = (idx >> 3) & 1023;
    int ko  = idx >> 13;
    int k   = ko * 8 + j;
    float v = (k < 64) ? Wx[k * 1024 + col] : Wh[(k - 64) * 1024 + col];
    wt[idx] = f2bf(v);
}

// ---------------- embed: one block per batch row b, all 128 timesteps -------
__global__ void __launch_bounds__(256)
embed_tiled(const float* __restrict__ obs, const float* __restrict__ act,
            const float* __restrict__ We,  const float* __restrict__ be,
            unsigned short* __restrict__ x) {
    int b   = blockIdx.x;
    int tid = threadIdx.x;
    __shared__ __align__(16) float A[128 * 84];
    __shared__ __align__(16) float W[80 * 64];

    for (int i = tid; i < 1280; i += 256)
        *reinterpret_cast<f32x4*>(&W[i * 4]) = *reinterpret_cast<const f32x4*>(&We[i * 4]);
    const float* ob = obs + (size_t)b * (TT * OBS);
#pragma unroll
    for (int it = 0; it < 8; ++it) {
        int i4 = tid + it * 256;
        f32x4 v = *reinterpret_cast<const f32x4*>(ob + i4 * 4);
        int e = i4 * 4, t = e >> 6, f = e & 63;
        *reinterpret_cast<f32x4*>(&A[t * 84 + f]) = v;
    }
    const float* ar = act + (size_t)b * (TT * ACT);
#pragma unroll
    for (int it = 0; it < 2; ++it) {
        int i4 = tid + it * 256;
        f32x4 v = *reinterpret_cast<const f32x4*>(ar + i4 * 4);
        int e = i4 * 4, t = e >> 4, f = e & 15;
        *reinterpret_cast<f32x4*>(&A[t * 84 + 64 + f]) = v;
    }
    __syncthreads();

    int rg = tid & 15, cg = tid >> 4;
    int c0 = cg * 4;
    float acc[8][4];
    float be0 = be[c0], be1 = be[c0 + 1], be2 = be[c0 + 2], be3 = be[c0 + 3];
#pragma unroll
    for (int i = 0; i < 8; ++i) {
        acc[i][0] = be0; acc[i][1] = be1; acc[i][2] = be2; acc[i][3] = be3;
    }

    for (int kq = 0; kq < 20; ++kq) {
        f32x4 A4[8];
#pragma unroll
        for (int i = 0; i < 8; ++i)
            A4[i] = *reinterpret_cast<const f32x4*>(&A[(rg + 16 * i) * 84 + kq * 4]);
        f32x4 W0 = *reinterpret_cast<const f32x4*>(&W[(kq * 4 + 0) * 64 + c0]);
        f32x4 W1 = *reinterpret_cast<const f32x4*>(&W[(kq * 4 + 1) * 64 + c0]);
        f32x4 W2 = *reinterpret_cast<const f32x4*>(&W[(kq * 4 + 2) * 64 + c0]);
        f32x4 W3 = *reinterpret_cast<const f32x4*>(&W[(kq * 4 + 3) * 64 + c0]);
#pragma unroll
        for (int i = 0; i < 8; ++i) {
#pragma unroll
            for (int j = 0; j < 4; ++j) {
                acc[i][j] += A4[i][0] * W0[j] + A4[i][1] * W1[j]
                           + A4[i][2] * W2[j] + A4[i][3] * W3[j];
            }
        }
    }

#pragma unroll
    for (int i = 0; i < 8; ++i) {
        int t = rg + 16 * i;
        unsigned int lo = (unsigned)f2bf(acc[i][0]) | ((unsigned)f2bf(acc[i][1]) << 16);
        unsigned int hi = (unsigned)f2bf(acc[i][2]) | ((unsigned)f2bf(acc[i][3]) << 16);
        *reinterpret_cast<uint2*>(x + ((size_t)t * BB + b) * DD + c0) = make_uint2(lo, hi);
    }
}

// ---------------- BN partial stats from bf16 x: p[t][slice][64] -------------
__global__ void stats_x(const unsigned short* __restrict__ x,
                        float* __restrict__ p1, float* __restrict__ p2) {
    int t = blockIdx.x, s = blockIdx.y;
    int tid = threadIdx.x;
    int dg = tid & 15, bl = tid >> 4;
    int d0 = dg * 4;
    float s1[4] = {0, 0, 0, 0}, s2[4] = {0, 0, 0, 0};
    const unsigned short* xt = x + (size_t)t * BB * DD;
    for (int it = 0; it < 32; ++it) {
        int b = s * 512 + it * 16 + bl;
        uint2 v = *reinterpret_cast<const uint2*>(xt + (size_t)b * DD + d0);
        const unsigned short* u = reinterpret_cast<const unsigned short*>(&v);
#pragma unroll
        for (int q = 0; q < 4; ++q) {
            float xv = bf2f(u[q]);
            s1[q] += xv; s2[q] += xv * xv;
        }
    }
    __shared__ float r1[16][64];
    __shared__ float r2[16][64];
#pragma unroll
    for (int q = 0; q < 4; ++q) { r1[bl][d0 + q] = s1[q]; r2[bl][d0 + q] = s2[q]; }
    __syncthreads();
    if (tid < 64) {
        float a = 0.f, b2 = 0.f;
        for (int g = 0; g < 16; ++g) { a += r1[g][tid]; b2 += r2[g][tid]; }
        size_t o = ((size_t)t * 8 + s) * 64 + tid;
        p1[o] = a; p2[o] = b2;
    }
}

// ---------------- BN stats finalize: a = rstd*scale, bb = bias - m*a ---------
__global__ void bn_stats(const float* __restrict__ p1, const float* __restrict__ p2,
                         const float* __restrict__ scale, const float* __restrict__ bias,
                         float* __restrict__ sa, float* __restrict__ sb) {
    int t = blockIdx.x, d = threadIdx.x;  // 64 threads
    float s1 = 0.f, s2 = 0.f;
    for (int c = 0; c < 8; ++c) {
        size_t o = ((size_t)t * 8 + c) * 64 + d;
        s1 += p1[o]; s2 += p2[o];
    }
    float m   = s1 * (1.0f / 4096.0f);
    float var = s2 * (1.0f / 4096.0f) - m * m;
    float a   = rsqrtf(var + 1e-5f) * scale[d];
    sa[t * 64 + d] = a;
    sb[t * 64 + d] = bias[d] - m * a;
}

// ---------------- BN apply + leaky ReLU (in-place on bf16 x) ----------------
__global__ void bn_apply(unsigned short* __restrict__ x,
                         const float* __restrict__ sa, const float* __restrict__ sb) {
    size_t e8 = (size_t)blockIdx.x * 256 + threadIdx.x;  // < T*B*8
    int d8  = (int)(e8 & 7);
    size_t row = e8 >> 3;            // t*B + b
    int t   = (int)(row >> 12);
    int d0  = d8 * 8;
    unsigned short* px = x + row * DD + d0;
    uint4 v = *reinterpret_cast<uint4*>(px);
    unsigned short* u = reinterpret_cast<unsigned short*>(&v);
    const float* a  = sa + t * 64 + d0;
    const float* bb = sb + t * 64 + d0;
#pragma unroll
    for (int q = 0; q < 8; ++q) {
        float xv = bf2f(u[q]);
        float y  = a[q] * xv + bb[q];
        y = (y >= 0.f) ? y : 0.2f * y;
        u[q] = f2bf(y);
    }
    *reinterpret_cast<uint4*>(px) = v;
}

// ---------------- fused LSTM with async weight pipeline ----------------------
// grid 128 x 512 threads (8 waves). Block owns 32 batch rows; wave w owns
// 32 hidden u (x4 gates). h in LDS A-tile, c in registers.
// Weights stream via global_load_lds into a 2-slot x 64KB LDS ring with
// counted vmcnt (never 0 in the loop): per K=32 iter i:
//   issue chunk i+1 (8 x gload_lds dwordx4) ; s_waitcnt vmcnt(8) ;
//   s_barrier ; ds_read + 16 MFMA ; s_barrier.
__global__ void __launch_bounds__(512)
lstm_fused(const unsigned short* __restrict__ x, const unsigned short* __restrict__ wt,
           unsigned short* __restrict__ hf, const float* __restrict__ b_lstm) {
    extern __shared__ __align__(16) unsigned short Adyn[];
    unsigned short* A  = Adyn;            // [32][ASTR]
    unsigned short* WR = Adyn + ATILE;    // 2 x WSLOT shorts

    int bid = blockIdx.x;
    int R0  = bid * 32;
    int tid = threadIdx.x;
    int lane = tid & 63, w = tid >> 6;    // wave 0..7
    int l15 = lane & 15, lhi = lane >> 4;
    int u0 = w * 32 + l15;

    // gate biases
    float bl[4][2];
#pragma unroll
    for (int g = 0; g < 4; ++g) {
        bl[g][0] = b_lstm[g * 256 + u0];
        bl[g][1] = b_lstm[g * 256 + u0 + 16];
    }

    // x staging mapping: every thread handles 8B (uniform vmem count across waves)
    int xr = tid >> 4;            // 0..31 row
    int xc = (tid & 15) * 4;      // d 0..60

    // ---- init: zero h region, stage x_0 (already BN-applied) ----
    {
        uint4 z = make_uint4(0, 0, 0, 0);
#pragma unroll
        for (int i = 0; i < 2; ++i) {
            int idx = tid + i * 512;          // < 1024 = 32 rows * 32 octs
            int row = idx >> 5, oct = idx & 31;
            *reinterpret_cast<uint4*>(&A[row * ASTR + 64 + oct * 8]) = z;
        }
        uint2 v0 = *reinterpret_cast<const uint2*>(x + ((size_t)(R0 + xr)) * DD + xc);
        *reinterpret_cast<uint2*>(&A[xr * ASTR + xc]) = v0;
    }

    // c state in registers
    float creg[2][2][4];
#pragma unroll
    for (int m = 0; m < 2; ++m)
#pragma unroll
        for (int s = 0; s < 2; ++s)
#pragma unroll
            for (int r = 0; r < 4; ++r) creg[m][s][r] = 0.f;

    // staging: chunk = 64KB (K=32). per thread: 8 x 16B. wave q-offsets.
    const char* wtb = (const char*)wt;
    int gbase = w * 8192 + lane * 16;     // byte offset within chunk for this lane
    int lbase = (ATILE * 2) + w * 8192;   // byte offset of wave region in WR slot 0

#define STAGE(SRC, SLOT)                                                          \
    {                                                                             \
        const char* gsrc = wtb + (size_t)(SRC) * 65536 + gbase;                   \
        char* ldst = (char*)Adyn + lbase + (SLOT) * 65536;                        \
        _Pragma("unroll")                                                         \
        for (int q = 0; q < 8; ++q)                                               \
            __builtin_amdgcn_global_load_lds((gas_t)(gsrc + q * 1024),            \
                                             (las_t)(ldst + q * 1024), 16, 0, 0); \
    }

    // prologue: chunk 0 -> slot 0, full drain once
    STAGE(0, 0);
    __syncthreads();

    int aoff = l15 * ASTR + lhi * 8;
    const unsigned short* wfix = WR + lhi * 4096 + u0 * 8;  // lhi*8192 shorts/2... (shorts: lhi*8192/2? no)
    // NOTE: keep address math in shorts: slot base WR + slot*WSLOT; lane base lhi*8192 + u0*8
    uint2 xreg;

    for (int t = 0; t < TT; ++t) {
        f32x4 acc[2][4][2];
#pragma unroll
        for (int m = 0; m < 2; ++m)
#pragma unroll
            for (int g = 0; g < 4; ++g)
#pragma unroll
                for (int s = 0; s < 2; ++s) acc[m][g][s] = (f32x4)0.f;

        int tl = (t + 1 < TT) ? t + 1 : t;   // last step loads dummy (uniform count)

#pragma unroll
        for (int i = 0; i < 10; ++i) {
            if (i == 6) {
                // x prefetch rides the vmem queue between C6 and C7
                xreg = *reinterpret_cast<const uint2*>(
                    x + ((size_t)tl * BB + R0 + xr) * DD + xc);
            }
            STAGE((i + 1) % 10, (i + 1) & 1);
            if (i == 6) {
                asm volatile("s_waitcnt vmcnt(9)" ::: "memory");
            } else {
                asm volatile("s_waitcnt vmcnt(8)" ::: "memory");
            }
            __builtin_amdgcn_s_barrier();
            __builtin_amdgcn_sched_barrier(0);

            const unsigned short* ws = WR + (i & 1) * WSLOT + lhi * 8192 + u0 * 8;
            bshort8 a0 = *reinterpret_cast<const bshort8*>(&A[aoff + i * 32]);
            bshort8 a1 = *reinterpret_cast<const bshort8*>(&A[aoff + 16 * ASTR + i * 32]);
#pragma unroll
            for (int g = 0; g < 4; ++g) {
#pragma unroll
                for (int s = 0; s < 2; ++s) {
                    bshort8 b = *reinterpret_cast<const bshort8*>(ws + g * 2048 + s * 128);
                    acc[0][g][s] = __builtin_amdgcn_mfma_f32_16x16x32_bf16(a0, b, acc[0][g][s], 0, 0, 0);
                    acc[1][g][s] = __builtin_amdgcn_mfma_f32_16x16x32_bf16(a1, b, acc[1][g][s], 0, 0, 0);
                }
            }
            __builtin_amdgcn_sched_barrier(0);
            __builtin_amdgcn_s_barrier();      // protect ring slot before next issue
            __builtin_amdgcn_sched_barrier(0);
        }

        // ---- gates + state update ----
        bool last = (t == TT - 1);
#pragma unroll
        for (int m = 0; m < 2; ++m) {
#pragma unroll
            for (int s = 0; s < 2; ++s) {
                int us = u0 + s * 16;
#pragma unroll
                for (int r = 0; r < 4; ++r) {
                    int row = m * 16 + lhi * 4 + r;
                    float zi = acc[m][0][s][r] + bl[0][s];
                    float zf = acc[m][1][s][r] + bl[1][s];
                    float zg = acc[m][2][s][r] + bl[2][s];
                    float zo = acc[m][3][s][r] + bl[3][s];
                    float si = 1.f / (1.f + __expf(-zi));
                    float sf = 1.f / (1.f + __expf(-zf));
                    float so = 1.f / (1.f + __expf(-zo));
                    float tg = 2.f / (1.f + __expf(-2.f * zg)) - 1.f;
                    float cn = sf * creg[m][s][r] + si * tg;
                    float tc = 2.f / (1.f + __expf(-2.f * cn)) - 1.f;
                    creg[m][s][r] = cn;
                    unsigned short hb = f2bf(so * tc);
                    if (last)
                        hf[(size_t)(R0 + row) * HH + us] = hb;
                    else
                        A[row * ASTR + 64 + us] = hb;
                }
            }
        }
        // stage x_{t+1} into A (skip meaningless write on last step)
        if (!last)
            *reinterpret_cast<uint2*>(&A[xr * ASTR + xc]) = xreg;

        asm volatile("s_waitcnt lgkmcnt(0)" ::: "memory");
        __builtin_amdgcn_s_barrier();
        __builtin_amdgcn_sched_barrier(0);
    }
    asm volatile("s_waitcnt vmcnt(0)" ::: "memory");  // drain tail stages
#undef STAGE
}

// ---------------- heads: mu = h@Wmu + bmu ; log_std clipped ------------------
__global__ void heads(const unsigned short* __restrict__ h,
                      const float* __restrict__ Wmu, const float* __restrict__ bmu,
                      const float* __restrict__ Wls, const float* __restrict__ bls,
                      float* __restrict__ out) {
    int tid = threadIdx.x;
    int b = blockIdx.x * 4 + (tid >> 6);
    int d = tid & 63;
    const unsigned short* hr = h + (size_t)b * HH;
    float mu = 0.f, ls = 0.f;
    for (int k = 0; k < HH; ++k) {
        float hv = bf2f(hr[k]);
        mu += hv * Wmu[k * 64 + d];
        ls += hv * Wls[k * 64 + d];
    }
    mu += bmu[d];
    ls += bls[d];
    ls = fminf(fmaxf(ls, -10.f), 2.f);
    out[(size_t)b * 64 + d] = mu;
    out[BD + (size_t)b * 64 + d] = ls;
}

extern "C" void kernel_launch(void* const* d_in, const int* in_sizes, int n_in,
                              void* d_out, int out_size, void* d_ws, size_t ws_size,
                              hipStream_t stream) {
    const float* obs = (const float*)d_in[0];
    const float* act = (const float*)d_in[1];
    const float* We  = (const float*)d_in[2];
    const float* be  = (const float*)d_in[3];
    const float* bns = (const float*)d_in[4];
    const float* bnb = (const float*)d_in[5];
    const float* Wx  = (const float*)d_in[6];
    const float* Wh  = (const float*)d_in[7];
    const float* bl  = (const float*)d_in[8];
    const float* Wmu = (const float*)d_in[9];
    const float* bmu = (const float*)d_in[10];
    const float* Wls = (const float*)d_in[11];
    const float* bls = (const float*)d_in[12];

    char* ws = (char*)d_ws;
    unsigned short* xbf = (unsigned short*)(ws + 0);            // 64MB x (BN-applied after bn_apply)
    unsigned short* wt  = (unsigned short*)(ws + 67108864);     // 640KB
    unsigned short* hfin= (unsigned short*)(ws + 67764224);     // 2MB (final h)
    float* p1           = (float*)(ws + 76152832);              // 256KB
    float* p2           = (float*)(ws + 78249984);              // 256KB
    float* sa           = (float*)(ws + 80347136);              // 32KB
    float* sb           = (float*)(ws + 80379904);              // 32KB

    pack_wt<<<1280, 256, 0, stream>>>(Wx, Wh, wt);
    embed_tiled<<<4096, 256, 0, stream>>>(obs, act, We, be, xbf);
    stats_x<<<dim3(128, 8), 256, 0, stream>>>(xbf, p1, p2);
    bn_stats<<<128, 64, 0, stream>>>(p1, p2, bns, bnb, sa, sb);
    bn_apply<<<16384, 256, 0, stream>>>(xbf, sa, sb);

    // dynamic LDS: A (20736B) + 2 x 64KB weight ring = 151808B -> 1 block/CU
    lstm_fused<<<128, 512, 151808, stream>>>(xbf, wt, hfin, bl);

    heads<<<1024, 256, 0, stream>>>(hfin, Wmu, bmu, Wls, bls, (float*)d_out);
}

// Round 8
// 2729.779 us; speedup vs baseline: 1.9802x; 1.0196x over previous
//
#include <hip/hip_runtime.h>
#include <hip/hip_bf16.h>

// Problem constants
#define BB   4096
#define TT   128
#define OBS  64
#define ACT  16
#define DD   64
#define HH   256
#define G4   1024   // 4*H
#define BD   262144 // B*D

// LDS A-tile row stride in shorts: 320 data + 4 pad.
#define ASTR 324
#define ATILE (32 * ASTR)

typedef short bshort8 __attribute__((ext_vector_type(8)));
typedef float f32x4  __attribute__((ext_vector_type(4)));

__device__ __forceinline__ unsigned short f2bf(float f) {
    union { float f; unsigned int u; } v; v.f = f;
    unsigned int u = v.u;
    u += 0x7FFFu + ((u >> 16) & 1u);   // RNE
    return (unsigned short)(u >> 16);
}
__device__ __forceinline__ float bf2f(unsigned short s) {
    union { unsigned int u; float f; } v; v.u = ((unsigned int)s) << 16;
    return v.f;
}

// ---------------- pack weights: Wt[ko][col][j] = B[8*ko+j][col], bf16 -------
// B = [Wx (64 rows) ; Wh (256 rows)] -> K = 320 = 40 k-octs, 1024 cols
__global__ void pack_wt(const float* __restrict__ Wx, const float* __restrict__ Wh,
                        unsigned short* __restrict__ wt) {
    int idx = blockIdx.x * 256 + threadIdx.x;      // < 40*1024*8 = 327680
    int j   = idx & 7;
    int col = (idx >> 3) & 1023;
    int ko  = idx >> 13;
    int k   = ko * 8 + j;
    float v = (k < 64) ? Wx[k * 1024 + col] : Wh[(k - 64) * 1024 + col];
    wt[idx] = f2bf(v);
}

// ---------------- embed: one block per batch row b, all 128 timesteps -------
__global__ void __launch_bounds__(256)
embed_tiled(const float* __restrict__ obs, const float* __restrict__ act,
            const float* __restrict__ We,  const float* __restrict__ be,
            unsigned short* __restrict__ x) {
    int b   = blockIdx.x;
    int tid = threadIdx.x;
    __shared__ __align__(16) float A[128 * 84];
    __shared__ __align__(16) float W[80 * 64];

    for (int i = tid; i < 1280; i += 256)
        *reinterpret_cast<f32x4*>(&W[i * 4]) = *reinterpret_cast<const f32x4*>(&We[i * 4]);
    const float* ob = obs + (size_t)b * (TT * OBS);
#pragma unroll
    for (int it = 0; it < 8; ++it) {
        int i4 = tid + it * 256;
        f32x4 v = *reinterpret_cast<const f32x4*>(ob + i4 * 4);
        int e = i4 * 4, t = e >> 6, f = e & 63;
        *reinterpret_cast<f32x4*>(&A[t * 84 + f]) = v;
    }
    const float* ar = act + (size_t)b * (TT * ACT);
#pragma unroll
    for (int it = 0; it < 2; ++it) {
        int i4 = tid + it * 256;
        f32x4 v = *reinterpret_cast<const f32x4*>(ar + i4 * 4);
        int e = i4 * 4, t = e >> 4, f = e & 15;
        *reinterpret_cast<f32x4*>(&A[t * 84 + 64 + f]) = v;
    }
    __syncthreads();

    int rg = tid & 15, cg = tid >> 4;
    int c0 = cg * 4;
    float acc[8][4];
    float be0 = be[c0], be1 = be[c0 + 1], be2 = be[c0 + 2], be3 = be[c0 + 3];
#pragma unroll
    for (int i = 0; i < 8; ++i) {
        acc[i][0] = be0; acc[i][1] = be1; acc[i][2] = be2; acc[i][3] = be3;
    }

    for (int kq = 0; kq < 20; ++kq) {
        f32x4 A4[8];
#pragma unroll
        for (int i = 0; i < 8; ++i)
            A4[i] = *reinterpret_cast<const f32x4*>(&A[(rg + 16 * i) * 84 + kq * 4]);
        f32x4 W0 = *reinterpret_cast<const f32x4*>(&W[(kq * 4 + 0) * 64 + c0]);
        f32x4 W1 = *reinterpret_cast<const f32x4*>(&W[(kq * 4 + 1) * 64 + c0]);
        f32x4 W2 = *reinterpret_cast<const f32x4*>(&W[(kq * 4 + 2) * 64 + c0]);
        f32x4 W3 = *reinterpret_cast<const f32x4*>(&W[(kq * 4 + 3) * 64 + c0]);
#pragma unroll
        for (int i = 0; i < 8; ++i) {
#pragma unroll
            for (int j = 0; j < 4; ++j) {
                acc[i][j] += A4[i][0] * W0[j] + A4[i][1] * W1[j]
                           + A4[i][2] * W2[j] + A4[i][3] * W3[j];
            }
        }
    }

#pragma unroll
    for (int i = 0; i < 8; ++i) {
        int t = rg + 16 * i;
        unsigned int lo = (unsigned)f2bf(acc[i][0]) | ((unsigned)f2bf(acc[i][1]) << 16);
        unsigned int hi = (unsigned)f2bf(acc[i][2]) | ((unsigned)f2bf(acc[i][3]) << 16);
        *reinterpret_cast<uint2*>(x + ((size_t)t * BB + b) * DD + c0) = make_uint2(lo, hi);
    }
}

// ---------------- BN partial stats from bf16 x: p[t][slice][64] -------------
__global__ void stats_x(const unsigned short* __restrict__ x,
                        float* __restrict__ p1, float* __restrict__ p2) {
    int t = blockIdx.x, s = blockIdx.y;
    int tid = threadIdx.x;
    int dg = tid & 15, bl = tid >> 4;
    int d0 = dg * 4;
    float s1[4] = {0, 0, 0, 0}, s2[4] = {0, 0, 0, 0};
    const unsigned short* xt = x + (size_t)t * BB * DD;
    for (int it = 0; it < 32; ++it) {
        int b = s * 512 + it * 16 + bl;
        uint2 v = *reinterpret_cast<const uint2*>(xt + (size_t)b * DD + d0);
        const unsigned short* u = reinterpret_cast<const unsigned short*>(&v);
#pragma unroll
        for (int q = 0; q < 4; ++q) {
            float xv = bf2f(u[q]);
            s1[q] += xv; s2[q] += xv * xv;
        }
    }
    __shared__ float r1[16][64];
    __shared__ float r2[16][64];
#pragma unroll
    for (int q = 0; q < 4; ++q) { r1[bl][d0 + q] = s1[q]; r2[bl][d0 + q] = s2[q]; }
    __syncthreads();
    if (tid < 64) {
        float a = 0.f, b2 = 0.f;
        for (int g = 0; g < 16; ++g) { a += r1[g][tid]; b2 += r2[g][tid]; }
        size_t o = ((size_t)t * 8 + s) * 64 + tid;
        p1[o] = a; p2[o] = b2;
    }
}

// ---------------- BN stats finalize: a = rstd*scale, bb = bias - m*a ---------
__global__ void bn_stats(const float* __restrict__ p1, const float* __restrict__ p2,
                         const float* __restrict__ scale, const float* __restrict__ bias,
                         float* __restrict__ sa, float* __restrict__ sb) {
    int t = blockIdx.x, d = threadIdx.x;  // 64 threads
    float s1 = 0.f, s2 = 0.f;
    for (int c = 0; c < 8; ++c) {
        size_t o = ((size_t)t * 8 + c) * 64 + d;
        s1 += p1[o]; s2 += p2[o];
    }
    float m   = s1 * (1.0f / 4096.0f);
    float var = s2 * (1.0f / 4096.0f) - m * m;
    float a   = rsqrtf(var + 1e-5f) * scale[d];
    sa[t * 64 + d] = a;
    sb[t * 64 + d] = bias[d] - m * a;
}

// ---------------- fused LSTM: block owns 32 batch rows, NO cross-block dep ---
// grid 128 x 512 threads (8 waves). Wave w owns u-slice w*32..+31 for all 4
// gates. h lives in LDS, c in registers. One barrier per step (A dbuf).
// ROUND 8 CHANGE: per-block K-chunk PHASE ROTATION. All blocks previously
// streamed the same 640KB in the same order in lockstep -> same-address L2
// hotspot (measured: ~4000cy stall per chunk). Block slot s starts at chunk
// (s%10) and walks (phase+i)%10 -> 16 blocks/XCD spread over all 10 chunk
// windows. K-sum order change is numerically irrelevant (fp32 acc).
__global__ void __launch_bounds__(512, 2)
lstm_fused(const unsigned short* __restrict__ x, const unsigned short* __restrict__ wt,
           const float* __restrict__ sa, const float* __restrict__ sb,
           unsigned short* __restrict__ hf, const float* __restrict__ b_lstm) {
    extern __shared__ __align__(16) unsigned short Adyn[];  // 2 x [32][ASTR]

    int bid = blockIdx.x;
    int R0  = bid * 32;                 // first batch row owned by this block
    int tid = threadIdx.x;
    int lane = tid & 63, w = tid >> 6;  // wave 0..7
    int l15 = lane & 15, lhi = lane >> 4;
    int u0 = w * 32 + l15;              // hidden col base (s adds 16)

    // phase: spread chunk order across blocks sharing an XCD (bid%8 = XCD rr)
    int phase = (bid >> 3) % 10;

    // gate biases for this thread's two columns
    float bl[4][2];
#pragma unroll
    for (int g = 0; g < 4; ++g) {
        bl[g][0] = b_lstm[g * 256 + u0];
        bl[g][1] = b_lstm[g * 256 + u0 + 16];
    }

    // ---- init buffer 0: zero h region (k=64..319), stage x_0 with BN fold ----
    {
        uint4 z = make_uint4(0, 0, 0, 0);
#pragma unroll
        for (int i = 0; i < 2; ++i) {
            int idx = tid + i * 512;    // < 1024 = 32 rows * 32 octs
            int row = idx >> 5, oct = idx & 31;
            *reinterpret_cast<uint4*>(&Adyn[row * ASTR + 64 + oct * 8]) = z;
        }
    }
    int xrow = tid >> 3, xoct = tid & 7, d0x = (tid & 7) * 8;
    if (tid < 256) {
        f32x4 a0 = *reinterpret_cast<const f32x4*>(sa + d0x);
        f32x4 a1 = *reinterpret_cast<const f32x4*>(sa + d0x + 4);
        f32x4 b0 = *reinterpret_cast<const f32x4*>(sb + d0x);
        f32x4 b1 = *reinterpret_cast<const f32x4*>(sb + d0x + 4);
        uint4 v = *reinterpret_cast<const uint4*>(x + ((size_t)(R0 + xrow)) * DD + d0x);
        unsigned short* uu = reinterpret_cast<unsigned short*>(&v);
#pragma unroll
        for (int q = 0; q < 4; ++q) {
            float y = a0[q] * bf2f(uu[q]) + b0[q];
            uu[q] = f2bf(y >= 0.f ? y : 0.2f * y);
            float y2 = a1[q] * bf2f(uu[4 + q]) + b1[q];
            uu[4 + q] = f2bf(y2 >= 0.f ? y2 : 0.2f * y2);
        }
        *reinterpret_cast<uint4*>(&Adyn[xrow * ASTR + xoct * 8]) = v;
    }

    // c state in registers
    float creg[2][2][4];
#pragma unroll
    for (int m = 0; m < 2; ++m)
#pragma unroll
        for (int s = 0; s < 2; ++s)
#pragma unroll
            for (int r = 0; r < 4; ++r) creg[m][s][r] = 0.f;

    const unsigned short* wb = wt + ((size_t)lhi * 1024 + u0) * 8;
    int aoff = l15 * ASTR + lhi * 8;

    // ---- weight pipeline prologue: wf[0] <- chunk 'phase' ----
    bshort8 wf[2][4][2];
    {
        const unsigned short* wk0 = wb + (size_t)phase * 32768;
#pragma unroll
        for (int g = 0; g < 4; ++g)
#pragma unroll
            for (int s = 0; s < 2; ++s)
                wf[0][g][s] = *reinterpret_cast<const bshort8*>(wk0 + g * 2048 + s * 128);
    }

    __syncthreads();

    for (int t = 0; t < TT; ++t) {
        unsigned short* Acur = Adyn + (t & 1) * ATILE;
        unsigned short* Anxt = Adyn + ((t + 1) & 1) * ATILE;

        // ---- prefetch x_{t+1} + BN coeffs (lands during k-loop) ----
        uint4 pf;
        f32x4 pa0, pa1, pb0, pb1;
        bool do_pf = (t + 1 < TT) && (tid < 256);
        if (do_pf) {
            pf  = *reinterpret_cast<const uint4*>(x + ((size_t)(t + 1) * BB + R0 + xrow) * DD + d0x);
            pa0 = *reinterpret_cast<const f32x4*>(sa + (t + 1) * 64 + d0x);
            pa1 = *reinterpret_cast<const f32x4*>(sa + (t + 1) * 64 + d0x + 4);
            pb0 = *reinterpret_cast<const f32x4*>(sb + (t + 1) * 64 + d0x);
            pb1 = *reinterpret_cast<const f32x4*>(sb + (t + 1) * 64 + d0x + 4);
        }

        // ---- k-loop: z = A @ W, phase-rotated chunk order ----
        f32x4 acc[2][4][2];
#pragma unroll
        for (int m = 0; m < 2; ++m)
#pragma unroll
            for (int g = 0; g < 4; ++g)
#pragma unroll
                for (int s = 0; s < 2; ++s) acc[m][g][s] = (f32x4)0.f;

#pragma unroll
        for (int i = 0; i < 10; ++i) {
            const int cb = i & 1, nb = cb ^ 1;
            int ci = phase + i;     if (ci >= 10) ci -= 10;   // current chunk
            int cn = phase + i + 1; if (cn >= 10) cn -= 10;   // next chunk (i=9 wraps to next step's first)
            const unsigned short* wk = wb + (size_t)cn * 32768;
#pragma unroll
            for (int g = 0; g < 4; ++g)
#pragma unroll
                for (int s = 0; s < 2; ++s)
                    wf[nb][g][s] = *reinterpret_cast<const bshort8*>(wk + g * 2048 + s * 128);

            bshort8 a0 = *reinterpret_cast<const bshort8*>(&Acur[aoff + ci * 32]);
            bshort8 a1 = *reinterpret_cast<const bshort8*>(&Acur[aoff + 16 * ASTR + ci * 32]);
#pragma unroll
            for (int g = 0; g < 4; ++g) {
#pragma unroll
                for (int s = 0; s < 2; ++s) {
                    acc[0][g][s] = __builtin_amdgcn_mfma_f32_16x16x32_bf16(a0, wf[cb][g][s], acc[0][g][s], 0, 0, 0);
                    acc[1][g][s] = __builtin_amdgcn_mfma_f32_16x16x32_bf16(a1, wf[cb][g][s], acc[1][g][s], 0, 0, 0);
                }
            }
        }

        // ---- gates + state update; h_t -> Anxt (global on last step) ----
        bool last = (t == TT - 1);
#pragma unroll
        for (int m = 0; m < 2; ++m) {
#pragma unroll
            for (int s = 0; s < 2; ++s) {
                int us = u0 + s * 16;
#pragma unroll
                for (int r = 0; r < 4; ++r) {
                    int row = m * 16 + lhi * 4 + r;
                    float zi = acc[m][0][s][r] + bl[0][s];
                    float zf = acc[m][1][s][r] + bl[1][s];
                    float zg = acc[m][2][s][r] + bl[2][s];
                    float zo = acc[m][3][s][r] + bl[3][s];
                    float si = 1.f / (1.f + __expf(-zi));
                    float sf = 1.f / (1.f + __expf(-zf));
                    float so = 1.f / (1.f + __expf(-zo));
                    float tg = 2.f / (1.f + __expf(-2.f * zg)) - 1.f;
                    float cn2 = sf * creg[m][s][r] + si * tg;
                    float tc = 2.f / (1.f + __expf(-2.f * cn2)) - 1.f;
                    creg[m][s][r] = cn2;
                    unsigned short hb = f2bf(so * tc);
                    if (last)
                        hf[(size_t)(R0 + row) * HH + us] = hb;
                    else
                        Anxt[row * ASTR + 64 + us] = hb;
                }
            }
        }
        // ---- stage prefetched x_{t+1} into Anxt ----
        if (do_pf) {
            unsigned short* uu = reinterpret_cast<unsigned short*>(&pf);
#pragma unroll
            for (int q = 0; q < 4; ++q) {
                float y = pa0[q] * bf2f(uu[q]) + pb0[q];
                uu[q] = f2bf(y >= 0.f ? y : 0.2f * y);
                float y2 = pa1[q] * bf2f(uu[4 + q]) + pb1[q];
                uu[4 + q] = f2bf(y2 >= 0.f ? y2 : 0.2f * y2);
            }
            *reinterpret_cast<uint4*>(&Anxt[xrow * ASTR + xoct * 8]) = pf;
        }
        __syncthreads();   // Anxt ready; Acur free for reuse
    }
}

// ---------------- heads: mu = h@Wmu + bmu ; log_std clipped ------------------
__global__ void heads(const unsigned short* __restrict__ h,
                      const float* __restrict__ Wmu, const float* __restrict__ bmu,
                      const float* __restrict__ Wls, const float* __restrict__ bls,
                      float* __restrict__ out) {
    int tid = threadIdx.x;
    int b = blockIdx.x * 4 + (tid >> 6);
    int d = tid & 63;
    const unsigned short* hr = h + (size_t)b * HH;
    float mu = 0.f, ls = 0.f;
    for (int k = 0; k < HH; ++k) {
        float hv = bf2f(hr[k]);
        mu += hv * Wmu[k * 64 + d];
        ls += hv * Wls[k * 64 + d];
    }
    mu += bmu[d];
    ls += bls[d];
    ls = fminf(fmaxf(ls, -10.f), 2.f);
    out[(size_t)b * 64 + d] = mu;
    out[BD + (size_t)b * 64 + d] = ls;
}

extern "C" void kernel_launch(void* const* d_in, const int* in_sizes, int n_in,
                              void* d_out, int out_size, void* d_ws, size_t ws_size,
                              hipStream_t stream) {
    const float* obs = (const float*)d_in[0];
    const float* act = (const float*)d_in[1];
    const float* We  = (const float*)d_in[2];
    const float* be  = (const float*)d_in[3];
    const float* bns = (const float*)d_in[4];
    const float* bnb = (const float*)d_in[5];
    const float* Wx  = (const float*)d_in[6];
    const float* Wh  = (const float*)d_in[7];
    const float* bl  = (const float*)d_in[8];
    const float* Wmu = (const float*)d_in[9];
    const float* bmu = (const float*)d_in[10];
    const float* Wls = (const float*)d_in[11];
    const float* bls = (const float*)d_in[12];

    char* ws = (char*)d_ws;
    unsigned short* xbf = (unsigned short*)(ws + 0);            // 64MB (raw pre-BN bf16)
    unsigned short* wt  = (unsigned short*)(ws + 67108864);     // 640KB
    unsigned short* hfin= (unsigned short*)(ws + 67764224);     // 2MB (final h)
    float* p1           = (float*)(ws + 76152832);              // 256KB
    float* p2           = (float*)(ws + 78249984);              // 256KB
    float* sa           = (float*)(ws + 80347136);              // 32KB
    float* sb           = (float*)(ws + 80379904);              // 32KB

    pack_wt<<<1280, 256, 0, stream>>>(Wx, Wh, wt);
    embed_tiled<<<4096, 256, 0, stream>>>(obs, act, We, be, xbf);
    stats_x<<<dim3(128, 8), 256, 0, stream>>>(xbf, p1, p2);
    bn_stats<<<128, 64, 0, stream>>>(p1, p2, bns, bnb, sa, sb);

    // dynamic LDS: 2*ATILE*2B = 82944 B (>80KB pins 1 block/CU)
    lstm_fused<<<128, 512, 82944, stream>>>(xbf, wt, sa, sb, hfin, bl);

    heads<<<1024, 256, 0, stream>>>(hfin, Wmu, bmu, Wls, bls, (float*)d_out);
}

// Round 9
// 1236.239 us; speedup vs baseline: 4.3725x; 2.2081x over previous
//
#include <hip/hip_runtime.h>
#include <hip/hip_bf16.h>

// Problem constants
#define BB   4096
#define TT   128
#define OBS  64
#define ACT  16
#define DD   64
#define HH   256
#define G4   1024   // 4*H
#define BD   262144 // B*D

// LDS A-tile row stride in shorts: 320 data + 4 pad.
#define ASTR 324

typedef short bshort8 __attribute__((ext_vector_type(8)));
typedef float f32x4  __attribute__((ext_vector_type(4)));

__device__ __forceinline__ unsigned short f2bf(float f) {
    union { float f; unsigned int u; } v; v.f = f;
    unsigned int u = v.u;
    u += 0x7FFFu + ((u >> 16) & 1u);   // RNE
    return (unsigned short)(u >> 16);
}
__device__ __forceinline__ float bf2f(unsigned short s) {
    union { unsigned int u; float f; } v; v.u = ((unsigned int)s) << 16;
    return v.f;
}

// ---------------- pack weights: Wt[ko][col][j] = B[8*ko+j][col], bf16 -------
// B = [Wx (64 rows) ; Wh (256 rows)] -> K = 320 = 40 k-octs, 1024 cols
__global__ void pack_wt(const float* __restrict__ Wx, const float* __restrict__ Wh,
                        unsigned short* __restrict__ wt) {
    int idx = blockIdx.x * 256 + threadIdx.x;      // < 40*1024*8 = 327680
    int j   = idx & 7;
    int col = (idx >> 3) & 1023;
    int ko  = idx >> 13;
    int k   = ko * 8 + j;
    float v = (k < 64) ? Wx[k * 1024 + col] : Wh[(k - 64) * 1024 + col];
    wt[idx] = f2bf(v);
}

// ---------------- embed: one block per batch row b, all 128 timesteps -------
__global__ void __launch_bounds__(256)
embed_tiled(const float* __restrict__ obs, const float* __restrict__ act,
            const float* __restrict__ We,  const float* __restrict__ be,
            unsigned short* __restrict__ x) {
    int b   = blockIdx.x;
    int tid = threadIdx.x;
    __shared__ __align__(16) float A[128 * 84];
    __shared__ __align__(16) float W[80 * 64];

    for (int i = tid; i < 1280; i += 256)
        *reinterpret_cast<f32x4*>(&W[i * 4]) = *reinterpret_cast<const f32x4*>(&We[i * 4]);
    const float* ob = obs + (size_t)b * (TT * OBS);
#pragma unroll
    for (int it = 0; it < 8; ++it) {
        int i4 = tid + it * 256;
        f32x4 v = *reinterpret_cast<const f32x4*>(ob + i4 * 4);
        int e = i4 * 4, t = e >> 6, f = e & 63;
        *reinterpret_cast<f32x4*>(&A[t * 84 + f]) = v;
    }
    const float* ar = act + (size_t)b * (TT * ACT);
#pragma unroll
    for (int it = 0; it < 2; ++it) {
        int i4 = tid + it * 256;
        f32x4 v = *reinterpret_cast<const f32x4*>(ar + i4 * 4);
        int e = i4 * 4, t = e >> 4, f = e & 15;
        *reinterpret_cast<f32x4*>(&A[t * 84 + 64 + f]) = v;
    }
    __syncthreads();

    int rg = tid & 15, cg = tid >> 4;
    int c0 = cg * 4;
    float acc[8][4];
    float be0 = be[c0], be1 = be[c0 + 1], be2 = be[c0 + 2], be3 = be[c0 + 3];
#pragma unroll
    for (int i = 0; i < 8; ++i) {
        acc[i][0] = be0; acc[i][1] = be1; acc[i][2] = be2; acc[i][3] = be3;
    }

    for (int kq = 0; kq < 20; ++kq) {
        f32x4 A4[8];
#pragma unroll
        for (int i = 0; i < 8; ++i)
            A4[i] = *reinterpret_cast<const f32x4*>(&A[(rg + 16 * i) * 84 + kq * 4]);
        f32x4 W0 = *reinterpret_cast<const f32x4*>(&W[(kq * 4 + 0) * 64 + c0]);
        f32x4 W1 = *reinterpret_cast<const f32x4*>(&W[(kq * 4 + 1) * 64 + c0]);
        f32x4 W2 = *reinterpret_cast<const f32x4*>(&W[(kq * 4 + 2) * 64 + c0]);
        f32x4 W3 = *reinterpret_cast<const f32x4*>(&W[(kq * 4 + 3) * 64 + c0]);
#pragma unroll
        for (int i = 0; i < 8; ++i) {
#pragma unroll
            for (int j = 0; j < 4; ++j) {
                acc[i][j] += A4[i][0] * W0[j] + A4[i][1] * W1[j]
                           + A4[i][2] * W2[j] + A4[i][3] * W3[j];
            }
        }
    }

#pragma unroll
    for (int i = 0; i < 8; ++i) {
        int t = rg + 16 * i;
        unsigned int lo = (unsigned)f2bf(acc[i][0]) | ((unsigned)f2bf(acc[i][1]) << 16);
        unsigned int hi = (unsigned)f2bf(acc[i][2]) | ((unsigned)f2bf(acc[i][3]) << 16);
        *reinterpret_cast<uint2*>(x + ((size_t)t * BB + b) * DD + c0) = make_uint2(lo, hi);
    }
}

// ---------------- BN partial stats from bf16 x: p[t][slice][64] -------------
__global__ void stats_x(const unsigned short* __restrict__ x,
                        float* __restrict__ p1, float* __restrict__ p2) {
    int t = blockIdx.x, s = blockIdx.y;
    int tid = threadIdx.x;
    int dg = tid & 15, bl = tid >> 4;
    int d0 = dg * 4;
    float s1[4] = {0, 0, 0, 0}, s2[4] = {0, 0, 0, 0};
    const unsigned short* xt = x + (size_t)t * BB * DD;
    for (int it = 0; it < 32; ++it) {
        int b = s * 512 + it * 16 + bl;
        uint2 v = *reinterpret_cast<const uint2*>(xt + (size_t)b * DD + d0);
        const unsigned short* u = reinterpret_cast<const unsigned short*>(&v);
#pragma unroll
        for (int q = 0; q < 4; ++q) {
            float xv = bf2f(u[q]);
            s1[q] += xv; s2[q] += xv * xv;
        }
    }
    __shared__ float r1[16][64];
    __shared__ float r2[16][64];
#pragma unroll
    for (int q = 0; q < 4; ++q) { r1[bl][d0 + q] = s1[q]; r2[bl][d0 + q] = s2[q]; }
    __syncthreads();
    if (tid < 64) {
        float a = 0.f, b2 = 0.f;
        for (int g = 0; g < 16; ++g) { a += r1[g][tid]; b2 += r2[g][tid]; }
        size_t o = ((size_t)t * 8 + s) * 64 + tid;
        p1[o] = a; p2[o] = b2;
    }
}

// ---------------- BN stats finalize: a = rstd*scale, bb = bias - m*a ---------
__global__ void bn_stats(const float* __restrict__ p1, const float* __restrict__ p2,
                         const float* __restrict__ scale, const float* __restrict__ bias,
                         float* __restrict__ sa, float* __restrict__ sb) {
    int t = blockIdx.x, d = threadIdx.x;  // 64 threads
    float s1 = 0.f, s2 = 0.f;
    for (int c = 0; c < 8; ++c) {
        size_t o = ((size_t)t * 8 + c) * 64 + d;
        s1 += p1[o]; s2 += p2[o];
    }
    float m   = s1 * (1.0f / 4096.0f);
    float var = s2 * (1.0f / 4096.0f) - m * m;
    float a   = rsqrtf(var + 1e-5f) * scale[d];
    sa[t * 64 + d] = a;
    sb[t * 64 + d] = bias[d] - m * a;
}

// ---------------- LSTM step: 32-row x 64-u blocks, 2 blocks/CU ---------------
// grid (128 rg, 4 cg), 256 threads (4 waves). Block (rg,cg) owns rows
// rg*32..+31 and hidden cols cg*64..+63 of c/h: deterministic, zero races,
// sync via launch boundary. BN+leakyReLU folded into x staging. 1-deep
// register weight prefetch in the k-loop.
__global__ void lstm_step2(const unsigned short* __restrict__ x,
                           const unsigned short* __restrict__ wt,
                           const float* __restrict__ sa, const float* __restrict__ sb,
                           const unsigned short* __restrict__ h_prev,
                           unsigned short* __restrict__ h_next,
                           float* __restrict__ c_glob, const float* __restrict__ b_lstm,
                           int t) {
    __shared__ __align__(16) unsigned short A[32 * ASTR];
    int rg = blockIdx.x, cg = blockIdx.y;
    int R0 = rg * 32;
    int tid = threadIdx.x;

    // ---- stage x_t (BN fold): 32 rows x 64 d = 1 uint4/thread ----
    {
        int xrow = tid >> 3, d0x = (tid & 7) * 8;
        f32x4 a0 = *reinterpret_cast<const f32x4*>(sa + t * 64 + d0x);
        f32x4 a1 = *reinterpret_cast<const f32x4*>(sa + t * 64 + d0x + 4);
        f32x4 b0 = *reinterpret_cast<const f32x4*>(sb + t * 64 + d0x);
        f32x4 b1 = *reinterpret_cast<const f32x4*>(sb + t * 64 + d0x + 4);
        uint4 v = *reinterpret_cast<const uint4*>(x + ((size_t)t * BB + R0 + xrow) * DD + d0x);
        unsigned short* uu = reinterpret_cast<unsigned short*>(&v);
#pragma unroll
        for (int q = 0; q < 4; ++q) {
            float y = a0[q] * bf2f(uu[q]) + b0[q];
            uu[q] = f2bf(y >= 0.f ? y : 0.2f * y);
            float y2 = a1[q] * bf2f(uu[4 + q]) + b1[q];
            uu[4 + q] = f2bf(y2 >= 0.f ? y2 : 0.2f * y2);
        }
        *reinterpret_cast<uint4*>(&A[xrow * ASTR + d0x]) = v;
        // ---- stage h_{t-1}: 32 rows x 256 = 4 uint4/thread ----
        const unsigned short* hs = h_prev + (size_t)R0 * HH;
#pragma unroll
        for (int i = 0; i < 4; ++i) {
            int idx = tid + i * 256;
            int row = idx >> 5, kk = idx & 31;
            *reinterpret_cast<uint4*>(&A[row * ASTR + 64 + kk * 8]) =
                *reinterpret_cast<const uint4*>(hs + row * HH + kk * 8);
        }
    }
    __syncthreads();

    int lane = tid & 63, w = tid >> 6;   // 4 waves
    int l15 = lane & 15, lhi = lane >> 4;
    int u = cg * 64 + w * 16 + l15;      // this thread's hidden col
    const unsigned short* wb = wt + ((size_t)lhi * 1024 + u) * 8;
    int aoff = l15 * ASTR + lhi * 8;

    f32x4 acc[2][4];
#pragma unroll
    for (int m = 0; m < 2; ++m)
#pragma unroll
        for (int g = 0; g < 4; ++g) acc[m][g] = (f32x4)0.f;

    // k-loop with 1-deep register weight prefetch (iter i ko = i*4+lhi)
    bshort8 bw[2][4];
#pragma unroll
    for (int g = 0; g < 4; ++g)
        bw[0][g] = *reinterpret_cast<const bshort8*>(wb + g * 2048);

#pragma unroll
    for (int i = 0; i < 10; ++i) {
        const int cb = i & 1;
        if (i < 9) {
            const unsigned short* wk = wb + (size_t)(i + 1) * 32768;
#pragma unroll
            for (int g = 0; g < 4; ++g)
                bw[cb ^ 1][g] = *reinterpret_cast<const bshort8*>(wk + g * 2048);
        }
        bshort8 a0 = *reinterpret_cast<const bshort8*>(&A[aoff + i * 32]);
        bshort8 a1 = *reinterpret_cast<const bshort8*>(&A[aoff + 16 * ASTR + i * 32]);
#pragma unroll
        for (int g = 0; g < 4; ++g) {
            acc[0][g] = __builtin_amdgcn_mfma_f32_16x16x32_bf16(a0, bw[cb][g], acc[0][g], 0, 0, 0);
            acc[1][g] = __builtin_amdgcn_mfma_f32_16x16x32_bf16(a1, bw[cb][g], acc[1][g], 0, 0, 0);
        }
    }

    // ---- gates + state update (8 cells/thread) ----
    float bl0 = b_lstm[u], bl1 = b_lstm[256 + u], bl2 = b_lstm[512 + u], bl3 = b_lstm[768 + u];
#pragma unroll
    for (int m = 0; m < 2; ++m) {
#pragma unroll
        for (int r = 0; r < 4; ++r) {
            int row = m * 16 + lhi * 4 + r;
            size_t ci = (size_t)(R0 + row) * HH + u;
            float zi = acc[m][0][r] + bl0;
            float zf = acc[m][1][r] + bl1;
            float zg = acc[m][2][r] + bl2;
            float zo = acc[m][3][r] + bl3;
            float si = 1.f / (1.f + __expf(-zi));
            float sf = 1.f / (1.f + __expf(-zf));
            float so = 1.f / (1.f + __expf(-zo));
            float tg = 2.f / (1.f + __expf(-2.f * zg)) - 1.f;
            float cn = sf * c_glob[ci] + si * tg;
            float tc = 2.f / (1.f + __expf(-2.f * cn)) - 1.f;
            c_glob[ci] = cn;
            h_next[ci] = f2bf(so * tc);
        }
    }
}

// ---------------- heads: mu = h@Wmu + bmu ; log_std clipped ------------------
__global__ void heads(const unsigned short* __restrict__ h,
                      const float* __restrict__ Wmu, const float* __restrict__ bmu,
                      const float* __restrict__ Wls, const float* __restrict__ bls,
                      float* __restrict__ out) {
    int tid = threadIdx.x;
    int b = blockIdx.x * 4 + (tid >> 6);
    int d = tid & 63;
    const unsigned short* hr = h + (size_t)b * HH;
    float mu = 0.f, ls = 0.f;
    for (int k = 0; k < HH; ++k) {
        float hv = bf2f(hr[k]);
        mu += hv * Wmu[k * 64 + d];
        ls += hv * Wls[k * 64 + d];
    }
    mu += bmu[d];
    ls += bls[d];
    ls = fminf(fmaxf(ls, -10.f), 2.f);
    out[(size_t)b * 64 + d] = mu;
    out[BD + (size_t)b * 64 + d] = ls;
}

extern "C" void kernel_launch(void* const* d_in, const int* in_sizes, int n_in,
                              void* d_out, int out_size, void* d_ws, size_t ws_size,
                              hipStream_t stream) {
    const float* obs = (const float*)d_in[0];
    const float* act = (const float*)d_in[1];
    const float* We  = (const float*)d_in[2];
    const float* be  = (const float*)d_in[3];
    const float* bns = (const float*)d_in[4];
    const float* bnb = (const float*)d_in[5];
    const float* Wx  = (const float*)d_in[6];
    const float* Wh  = (const float*)d_in[7];
    const float* bl  = (const float*)d_in[8];
    const float* Wmu = (const float*)d_in[9];
    const float* bmu = (const float*)d_in[10];
    const float* Wls = (const float*)d_in[11];
    const float* bls = (const float*)d_in[12];

    char* ws = (char*)d_ws;
    unsigned short* xbf = (unsigned short*)(ws + 0);            // 64MB raw pre-BN bf16
    unsigned short* wt  = (unsigned short*)(ws + 67108864);     // 640KB
    unsigned short* h0  = (unsigned short*)(ws + 67764224);     // 2MB
    unsigned short* h1  = (unsigned short*)(ws + 69861376);     // 2MB
    float* cbuf         = (float*)(ws + 71958528);              // 4MB
    float* p1           = (float*)(ws + 76152832);              // 256KB
    float* p2           = (float*)(ws + 78249984);              // 256KB
    float* sa           = (float*)(ws + 80347136);              // 32KB
    float* sb           = (float*)(ws + 80379904);              // 32KB

    hipMemsetAsync(h0, 0, (size_t)BB * HH * 2, stream);
    hipMemsetAsync(cbuf, 0, (size_t)BB * HH * 4, stream);

    pack_wt<<<1280, 256, 0, stream>>>(Wx, Wh, wt);
    embed_tiled<<<4096, 256, 0, stream>>>(obs, act, We, be, xbf);
    stats_x<<<dim3(128, 8), 256, 0, stream>>>(xbf, p1, p2);
    bn_stats<<<128, 64, 0, stream>>>(p1, p2, bns, bnb, sa, sb);

    for (int t = 0; t < TT; ++t) {
        const unsigned short* hp = (t & 1) ? h1 : h0;
        unsigned short*       hn = (t & 1) ? h0 : h1;
        lstm_step2<<<dim3(128, 4), 256, 0, stream>>>(xbf, wt, sa, sb, hp, hn, cbuf, bl, t);
    }

    heads<<<1024, 256, 0, stream>>>(h0, Wmu, bmu, Wls, bls, (float*)d_out);
}